// Round 1
// baseline (532.187 us; speedup 1.0000x reference)
//
#include <hip/hip_runtime.h>
#include <hip/hip_bf16.h>

// Bilinear grid sample, align_corners=True, border clamp.
// x: [N, C, H, W] fp32; grid: [N, Ho, Wo, 2] fp32 in [-1, 1]; out: [N, C, Ho, Wo] fp32.
// Strategy: one thread per (n, ho, wo); compute coords/weights once, loop channels.

constexpr int N = 8, C = 64, H = 256, W = 256, HO = 256, WO = 256;
constexpr int NPIX = N * HO * WO;         // 524288 spatial output points
constexpr int PLANE = H * W;              // 65536 elements per channel plane

__global__ __launch_bounds__(256) void grid_sample_kernel(
    const float* __restrict__ x,
    const float* __restrict__ grid,
    float* __restrict__ out) {
    int idx = blockIdx.x * blockDim.x + threadIdx.x;
    if (idx >= NPIX) return;

    int wo = idx & (WO - 1);
    int ho = (idx >> 8) & (HO - 1);
    int n  = idx >> 16;

    // coalesced float2 grid load
    float2 g = ((const float2*)grid)[idx];
    float ix = (g.x + 1.0f) * 0.5f * (float)(W - 1);
    float iy = (g.y + 1.0f) * 0.5f * (float)(H - 1);

    float x0f = floorf(ix);
    float y0f = floorf(iy);
    float wx1 = ix - x0f;
    float wy1 = iy - y0f;
    float wx0 = 1.0f - wx1;
    float wy0 = 1.0f - wy1;

    int x0 = (int)fminf(fmaxf(x0f,        0.0f), (float)(W - 1));
    int x1 = (int)fminf(fmaxf(x0f + 1.0f, 0.0f), (float)(W - 1));
    int y0 = (int)fminf(fmaxf(y0f,        0.0f), (float)(H - 1));
    int y1 = (int)fminf(fmaxf(y0f + 1.0f, 0.0f), (float)(H - 1));

    float w00 = wy0 * wx0;
    float w01 = wy0 * wx1;
    float w10 = wy1 * wx0;
    float w11 = wy1 * wx1;

    int o00 = y0 * W + x0;
    int o01 = y0 * W + x1;
    int o10 = y1 * W + x0;
    int o11 = y1 * W + x1;

    const float* xn = x + (size_t)n * C * PLANE;
    float* on = out + (size_t)n * C * (HO * WO) + (size_t)ho * WO + wo;

#pragma unroll 4
    for (int c = 0; c < C; ++c) {
        const float* xc = xn + c * PLANE;
        float v = xc[o00] * w00 + xc[o01] * w01 + xc[o10] * w10 + xc[o11] * w11;
        __builtin_nontemporal_store(v, on + (size_t)c * (HO * WO));
    }
}

extern "C" void kernel_launch(void* const* d_in, const int* in_sizes, int n_in,
                              void* d_out, int out_size, void* d_ws, size_t ws_size,
                              hipStream_t stream) {
    const float* x    = (const float*)d_in[0];
    const float* grid = (const float*)d_in[1];
    float* out        = (float*)d_out;

    int threads = 256;
    int blocks = (NPIX + threads - 1) / threads;
    grid_sample_kernel<<<blocks, threads, 0, stream>>>(x, grid, out);
}

// Round 2
// 302.354 us; speedup vs baseline: 1.7601x; 1.7601x over previous
//
#include <hip/hip_runtime.h>
#include <hip/hip_bf16.h>

// Bilinear grid sample, align_corners=True, border clamp.
// x: [N, C, H, W] fp32; grid: [N, Ho, Wo, 2] fp32; out: [N, C, Ho, Wo] fp32.
//
// Two-pass strategy:
//   Pass 1: transpose x (NCHW) -> xt (NHWC) in d_ws. All coalesced.
//   Pass 2: wave-per-64-pixels, lane=channel. Each sample point's 64-channel
//           vector is a contiguous 256B read -> 4 coalesced loads per pixel
//           instead of 256 divergent 4B loads. Output transposed back via LDS.

constexpr int N = 8, C = 64, H = 256, W = 256, HO = 256, WO = 256;
constexpr int NPIX = N * HO * WO;          // 524288
constexpr int PLANE = H * W;               // 65536
constexpr size_t XT_BYTES = (size_t)N * C * PLANE * sizeof(float);  // 134 MB

// ---------------- Pass 1: NCHW -> NHWC transpose ----------------
// Block 256 = (64 px, 4 c). Tile: 64 channels x 64 pixels.
__global__ __launch_bounds__(256) void transpose_kernel(
    const float* __restrict__ x, float* __restrict__ xt) {
  __shared__ float tile[64][65];
  int tx = threadIdx.x;            // 0..63  (pixel in tile)
  int ty = threadIdx.y;            // 0..3
  int tileIdx = blockIdx.x;        // 8192 tiles
  int n = tileIdx >> 10;           // 1024 tiles per batch (65536/64)
  int pixb = (tileIdx & 1023) << 6;

  const float* xn = x + (size_t)n * C * PLANE;
#pragma unroll
  for (int k = 0; k < 16; ++k) {
    int c = (k << 2) + ty;
    tile[c][tx] = __builtin_nontemporal_load(&xn[(size_t)c * PLANE + pixb + tx]);
  }
  __syncthreads();
  float* xtn = xt + ((size_t)n * PLANE + pixb) * C;
#pragma unroll
  for (int k = 0; k < 16; ++k) {
    int p = (k << 2) + ty;
    xtn[(size_t)p * C + tx] = tile[tx][p];   // coalesced 256B store per wave
  }
}

// ---------------- Pass 2: gather with lane = channel ----------------
// Block 256 = 4 independent waves; each wave handles 64 consecutive pixels.
__global__ __launch_bounds__(256) void sample_kernel(
    const float* __restrict__ xt, const float* __restrict__ grid,
    float* __restrict__ out) {
  __shared__ float tile[4][64][33];   // [wave][channel][pixel-half] (+pad)
  __shared__ float4 wts[4][64];
  __shared__ int bs[4][64];

  int lane = threadIdx.x & 63;
  int wid = threadIdx.x >> 6;
  int gwave = blockIdx.x * 4 + wid;
  int pixb = gwave << 6;             // 64 pixels per wave, same n & row
  int p_idx = pixb + lane;
  int n = p_idx >> 16;

  // --- setup: per-lane pixel params ---
  float2 g = ((const float2*)grid)[p_idx];
  float ix = (g.x + 1.0f) * 0.5f * (float)(W - 1);
  float iy = (g.y + 1.0f) * 0.5f * (float)(H - 1);
  float x0f = floorf(ix), y0f = floorf(iy);
  float fx = ix - x0f, fy = iy - y0f;
  float cx0 = fminf(fmaxf(x0f,        0.f), (float)(W - 1));
  float cx1 = fminf(fmaxf(x0f + 1.f,  0.f), (float)(W - 1));
  float cy0 = fminf(fmaxf(y0f,        0.f), (float)(H - 1));
  float cy1 = fminf(fmaxf(y0f + 1.f,  0.f), (float)(H - 1));
  int x0 = (int)cx0, x1 = (int)cx1, y0 = (int)cy0, y1 = (int)cy1;
  int xl = min(x0, W - 2), yl = min(y0, H - 2);
  float wx0 = 1.f - fx, wx1 = fx, wy0 = 1.f - fy, wy1 = fy;
  // fold border clamp into weights on the fixed 2x2 footprint at (yl, xl)
  float wxl = (x0 == xl ? wx0 : 0.f) + (x1 == xl ? wx1 : 0.f);
  float wxh = (x0 == xl + 1 ? wx0 : 0.f) + (x1 == xl + 1 ? wx1 : 0.f);
  float wyl = (y0 == yl ? wy0 : 0.f) + (y1 == yl ? wy1 : 0.f);
  float wyh = (y0 == yl + 1 ? wy0 : 0.f) + (y1 == yl + 1 ? wy1 : 0.f);
  wts[wid][lane] = make_float4(wyl * wxl, wyl * wxh, wyh * wxl, wyh * wxh);
  bs[wid][lane] = ((n << 16) | (yl << 8) | xl) << 6;   // float index into xt
  __syncthreads();

  int prow = pixb & (PLANE - 1);     // ho*WO + wo0 within the image
  float* outn = out + (size_t)n * C * PLANE + prow;

  for (int h = 0; h < 2; ++h) {
    // --- gather: 32 pixels, lane = channel, 4 coalesced 256B loads each ---
#pragma unroll 4
    for (int q = 0; q < 32; ++q) {
      int p = (h << 5) + q;
      float4 wv = wts[wid][p];
      const float* src = xt + bs[wid][p] + lane;
      float a = src[0];
      float b = src[C];
      float cv = src[C * W];
      float d = src[C * W + C];
      tile[wid][lane][q] = a * wv.x + b * wv.y + cv * wv.z + d * wv.w;
    }
    __syncthreads();
    // --- writeback: 64 lanes = 2 channels x 32 pixels, coalesced 128B ---
    int pq = lane & 31;
    int cbase = lane >> 5;
#pragma unroll 8
    for (int k = 0; k < 32; ++k) {
      int c = (k << 1) + cbase;
      __builtin_nontemporal_store(tile[wid][c][pq],
                                  &outn[(size_t)c * PLANE + (h << 5) + pq]);
    }
    __syncthreads();
  }
}

// ---------------- Fallback (ws too small): original one-pass ----------------
__global__ __launch_bounds__(256) void grid_sample_fallback(
    const float* __restrict__ x, const float* __restrict__ grid,
    float* __restrict__ out) {
  int idx = blockIdx.x * blockDim.x + threadIdx.x;
  if (idx >= NPIX) return;
  int wo = idx & (WO - 1);
  int ho = (idx >> 8) & (HO - 1);
  int n  = idx >> 16;
  float2 g = ((const float2*)grid)[idx];
  float ix = (g.x + 1.0f) * 0.5f * (float)(W - 1);
  float iy = (g.y + 1.0f) * 0.5f * (float)(H - 1);
  float x0f = floorf(ix), y0f = floorf(iy);
  float wx1 = ix - x0f, wy1 = iy - y0f;
  float wx0 = 1.0f - wx1, wy0 = 1.0f - wy1;
  int x0 = (int)fminf(fmaxf(x0f,        0.0f), (float)(W - 1));
  int x1 = (int)fminf(fmaxf(x0f + 1.0f, 0.0f), (float)(W - 1));
  int y0 = (int)fminf(fmaxf(y0f,        0.0f), (float)(H - 1));
  int y1 = (int)fminf(fmaxf(y0f + 1.0f, 0.0f), (float)(H - 1));
  float w00 = wy0 * wx0, w01 = wy0 * wx1, w10 = wy1 * wx0, w11 = wy1 * wx1;
  int o00 = y0 * W + x0, o01 = y0 * W + x1, o10 = y1 * W + x0, o11 = y1 * W + x1;
  const float* xn = x + (size_t)n * C * PLANE;
  float* on = out + (size_t)n * C * PLANE + (size_t)ho * WO + wo;
#pragma unroll 4
  for (int c = 0; c < C; ++c) {
    const float* xc = xn + c * PLANE;
    float v = xc[o00] * w00 + xc[o01] * w01 + xc[o10] * w10 + xc[o11] * w11;
    __builtin_nontemporal_store(v, on + (size_t)c * PLANE);
  }
}

extern "C" void kernel_launch(void* const* d_in, const int* in_sizes, int n_in,
                              void* d_out, int out_size, void* d_ws, size_t ws_size,
                              hipStream_t stream) {
  const float* x    = (const float*)d_in[0];
  const float* grid = (const float*)d_in[1];
  float* out        = (float*)d_out;

  if (ws_size >= XT_BYTES) {
    float* xt = (float*)d_ws;
    transpose_kernel<<<N * PLANE / 64, dim3(64, 4), 0, stream>>>(x, xt);
    sample_kernel<<<NPIX / 256, 256, 0, stream>>>(xt, grid, out);
  } else {
    grid_sample_fallback<<<NPIX / 256, 256, 0, stream>>>(x, grid, out);
  }
}

// Round 3
// 276.456 us; speedup vs baseline: 1.9250x; 1.0937x over previous
//
#include <hip/hip_runtime.h>
#include <hip/hip_bf16.h>

// Bilinear grid sample, align_corners=True, border clamp.
// x: [N, C, H, W] fp32; grid: [N, Ho, Wo, 2] fp32; out: [N, C, Ho, Wo] fp32.
//
// Two-pass:
//   Pass 1: transpose x (NCHW fp32) -> xt (NHWC bf16) in d_ws. All coalesced.
//           bf16 halves the staging write and the gather-pass read traffic;
//           67 MB xt largely stays resident in the 256 MB L3.
//   Pass 2: one wave per 64 pixels, lane = channel. Per sample point: 4
//           coalesced 128B corner loads (bf16), fp32 interpolation, output
//           transposed back to NCHW through a padded LDS tile.

constexpr int N = 8, C = 64, H = 256, W = 256, HO = 256, WO = 256;
constexpr int NPIX = N * HO * WO;          // 524288
constexpr int PLANE = H * W;               // 65536
constexpr size_t XT_BYTES = (size_t)N * PLANE * C * sizeof(unsigned short); // 67 MB

__device__ __forceinline__ float bf16_to_f(unsigned short u) {
  union { unsigned int i; float f; } v;
  v.i = ((unsigned int)u) << 16;
  return v.f;
}

// ---------------- Pass 1: NCHW fp32 -> NHWC bf16 ----------------
// Block 256 = (64 px, 4 c). Tile: 64 channels x 64 pixels.
__global__ __launch_bounds__(256) void transpose_kernel(
    const float* __restrict__ x, unsigned int* __restrict__ xt) {
  __shared__ float tile[64][65];
  int tx = threadIdx.x;            // 0..63 (pixel in tile)
  int ty = threadIdx.y;            // 0..3
  int t = (ty << 6) + tx;
  int tileIdx = blockIdx.x;        // 8192 tiles
  int n = tileIdx >> 10;           // 1024 tiles per batch image
  int pixb = (tileIdx & 1023) << 6;

  const float* xn = x + (size_t)n * C * PLANE;
#pragma unroll
  for (int k = 0; k < 16; ++k) {
    int c = (k << 2) + ty;
    tile[c][tx] = __builtin_nontemporal_load(&xn[(size_t)c * PLANE + pixb + tx]);
  }
  __syncthreads();

  // xt as uint array (2 bf16 channels per word): word idx = pix*32 + chpair
  unsigned int* xtw = xt + ((size_t)(n * PLANE + pixb)) * 32;
  int chp = t & 31;                // channel pair 0..31 -> channels 2chp, 2chp+1
#pragma unroll
  for (int k = 0; k < 8; ++k) {
    int p = (k << 3) + (t >> 5);   // pixel within tile
    float f0 = tile[2 * chp][p];
    float f1 = tile[2 * chp + 1][p];
    __hip_bfloat162 h2 = __float22bfloat162_rn(make_float2(f0, f1));
    unsigned int w;
    __builtin_memcpy(&w, &h2, 4);  // low half = f0 (even channel)
    xtw[(size_t)p * 32 + chp] = w; // 256B contiguous per wave
  }
}

// ---------------- Pass 2: gather, lane = channel, 1 wave per block ----------------
__global__ __launch_bounds__(64) void sample_kernel(
    const unsigned short* __restrict__ xt, const float* __restrict__ grid,
    float* __restrict__ out) {
  __shared__ float tile[64][33];   // [channel][pixel-half] (+pad)
  __shared__ float4 wts[64];
  __shared__ int bs[64];

  int lane = threadIdx.x;
  int pixb = blockIdx.x << 6;      // 64 consecutive pixels, same n
  int p_idx = pixb + lane;
  int n = p_idx >> 16;

  // --- per-lane pixel params ---
  float2 g = ((const float2*)grid)[p_idx];
  float ix = (g.x + 1.0f) * 0.5f * (float)(W - 1);
  float iy = (g.y + 1.0f) * 0.5f * (float)(H - 1);
  float x0f = floorf(ix), y0f = floorf(iy);
  float fx = ix - x0f, fy = iy - y0f;
  float cx0 = fminf(fmaxf(x0f,        0.f), (float)(W - 1));
  float cx1 = fminf(fmaxf(x0f + 1.f,  0.f), (float)(W - 1));
  float cy0 = fminf(fmaxf(y0f,        0.f), (float)(H - 1));
  float cy1 = fminf(fmaxf(y0f + 1.f,  0.f), (float)(H - 1));
  int x0 = (int)cx0, x1 = (int)cx1, y0 = (int)cy0, y1 = (int)cy1;
  int xl = min(x0, W - 2), yl = min(y0, H - 2);
  float wx0 = 1.f - fx, wx1 = fx, wy0 = 1.f - fy, wy1 = fy;
  // fold border clamp into weights on the fixed 2x2 footprint at (yl, xl)
  float wxl = (x0 == xl ? wx0 : 0.f) + (x1 == xl ? wx1 : 0.f);
  float wxh = (x0 == xl + 1 ? wx0 : 0.f) + (x1 == xl + 1 ? wx1 : 0.f);
  float wyl = (y0 == yl ? wy0 : 0.f) + (y1 == yl ? wy1 : 0.f);
  float wyh = (y0 == yl + 1 ? wy0 : 0.f) + (y1 == yl + 1 ? wy1 : 0.f);
  wts[lane] = make_float4(wyl * wxl, wyl * wxh, wyh * wxl, wyh * wxh);
  bs[lane] = ((n << 16) | (yl << 8) | xl) << 6;  // bf16-element index into xt
  __syncthreads();

  int prow = pixb & (PLANE - 1);
  float* outn = out + (size_t)n * C * PLANE + prow;

  for (int h = 0; h < 2; ++h) {
    // --- gather: 32 pixels, 4 coalesced 128B bf16 loads each ---
#pragma unroll 8
    for (int q = 0; q < 32; ++q) {
      int p = (h << 5) + q;
      float4 wv = wts[p];
      const unsigned short* src = xt + bs[p] + lane;
      float a  = bf16_to_f(src[0]);
      float b  = bf16_to_f(src[C]);
      float cv = bf16_to_f(src[C * W]);
      float d  = bf16_to_f(src[C * W + C]);
      tile[lane][q] = a * wv.x + b * wv.y + cv * wv.z + d * wv.w;
    }
    __syncthreads();
    // --- writeback: 64 lanes = 2 channels x 32 pixels, coalesced ---
    int pq = lane & 31;
    int cb = lane >> 5;
#pragma unroll 8
    for (int k = 0; k < 32; ++k) {
      int c = (k << 1) + cb;
      __builtin_nontemporal_store(tile[c][pq],
                                  &outn[(size_t)c * PLANE + (h << 5) + pq]);
    }
    __syncthreads();
  }
}

// ---------------- Fallback (ws too small): one-pass direct ----------------
__global__ __launch_bounds__(256) void grid_sample_fallback(
    const float* __restrict__ x, const float* __restrict__ grid,
    float* __restrict__ out) {
  int idx = blockIdx.x * blockDim.x + threadIdx.x;
  if (idx >= NPIX) return;
  int wo = idx & (WO - 1);
  int ho = (idx >> 8) & (HO - 1);
  int n  = idx >> 16;
  float2 g = ((const float2*)grid)[idx];
  float ix = (g.x + 1.0f) * 0.5f * (float)(W - 1);
  float iy = (g.y + 1.0f) * 0.5f * (float)(H - 1);
  float x0f = floorf(ix), y0f = floorf(iy);
  float wx1 = ix - x0f, wy1 = iy - y0f;
  float wx0 = 1.0f - wx1, wy0 = 1.0f - wy1;
  int x0 = (int)fminf(fmaxf(x0f,        0.0f), (float)(W - 1));
  int x1 = (int)fminf(fmaxf(x0f + 1.0f, 0.0f), (float)(W - 1));
  int y0 = (int)fminf(fmaxf(y0f,        0.0f), (float)(H - 1));
  int y1 = (int)fminf(fmaxf(y0f + 1.0f, 0.0f), (float)(H - 1));
  float w00 = wy0 * wx0, w01 = wy0 * wx1, w10 = wy1 * wx0, w11 = wy1 * wx1;
  int o00 = y0 * W + x0, o01 = y0 * W + x1, o10 = y1 * W + x0, o11 = y1 * W + x1;
  const float* xn = x + (size_t)n * C * PLANE;
  float* on = out + (size_t)n * C * PLANE + (size_t)ho * WO + wo;
#pragma unroll 4
  for (int c = 0; c < C; ++c) {
    const float* xc = xn + c * PLANE;
    float v = xc[o00] * w00 + xc[o01] * w01 + xc[o10] * w10 + xc[o11] * w11;
    __builtin_nontemporal_store(v, on + (size_t)c * PLANE);
  }
}

extern "C" void kernel_launch(void* const* d_in, const int* in_sizes, int n_in,
                              void* d_out, int out_size, void* d_ws, size_t ws_size,
                              hipStream_t stream) {
  const float* x    = (const float*)d_in[0];
  const float* grid = (const float*)d_in[1];
  float* out        = (float*)d_out;

  if (ws_size >= XT_BYTES) {
    transpose_kernel<<<N * PLANE / 64, dim3(64, 4), 0, stream>>>(
        x, (unsigned int*)d_ws);
    sample_kernel<<<NPIX / 64, 64, 0, stream>>>(
        (const unsigned short*)d_ws, grid, out);
  } else {
    grid_sample_fallback<<<NPIX / 256, 256, 0, stream>>>(x, grid, out);
  }
}